// Round 3
// baseline (147.857 us; speedup 1.0000x reference)
//
#include <hip/hip_runtime.h>
#include <hip/hip_bf16.h>
#include <stdint.h>

using bf16 = __hip_bfloat16;
typedef __attribute__((ext_vector_type(8))) short bf16x8;
typedef __attribute__((ext_vector_type(4))) float f32x4;

// ---------------------------------------------------------------------------
// helpers
// ---------------------------------------------------------------------------
__device__ __forceinline__ void gload_lds16(const void* g, void* l) {
  __builtin_amdgcn_global_load_lds(
      (__attribute__((address_space(1))) void*)(g),
      (__attribute__((address_space(3))) void*)(l), 16, 0, 0);
}

__device__ __forceinline__ unsigned short bf16_bits(float f) {
  bf16 b = __float2bfloat16(f);
  return *reinterpret_cast<unsigned short*>(&b);
}

__device__ __forceinline__ float b2f(unsigned short u) {
  union { unsigned int i; float f; } x;
  x.i = ((unsigned int)u) << 16;
  return x.f;
}

// ---------------------------------------------------------------------------
// f32 -> bf16 conversion (float4 in, ushort4 out)
// ---------------------------------------------------------------------------
__global__ __launch_bounds__(256) void cvt_f32_bf16(
    const float* __restrict__ in, unsigned short* __restrict__ out, int n4) {
  int i = blockIdx.x * 256 + threadIdx.x;
  if (i >= n4) return;
  float4 f = reinterpret_cast<const float4*>(in)[i];
  ushort4 u;
  u.x = bf16_bits(f.x);
  u.y = bf16_bits(f.y);
  u.z = bf16_bits(f.z);
  u.w = bf16_bits(f.w);
  reinterpret_cast<ushort4*>(out)[i] = u;
}

// f32 [1024][1024] -> bf16 [1024][2048] duplicated ([W | W]) for residual-K
__global__ __launch_bounds__(256) void cvt_dup(const float* __restrict__ in,
                                               unsigned short* __restrict__ out) {
  int i = blockIdx.x * 256 + threadIdx.x;  // float4 index over [1024][1024]
  int r = i >> 8, c4 = (i & 255) * 4;
  float4 f = reinterpret_cast<const float4*>(in)[i];
  ushort4 u;
  u.x = bf16_bits(f.x);
  u.y = bf16_bits(f.y);
  u.z = bf16_bits(f.z);
  u.w = bf16_bits(f.w);
  *reinterpret_cast<ushort4*>(out + (size_t)r * 2048 + c4) = u;
  *reinterpret_cast<ushort4*>(out + (size_t)r * 2048 + 1024 + c4) = u;
}

// ---------------------------------------------------------------------------
// f32 [R][C] -> bf16 transpose out_t [C][R] (+ optional direct bf16 copy).
// 64x64 tiles via LDS; tile stride 79 breaks bank-conflict power-of-2.
// ---------------------------------------------------------------------------
template <int DIRECT>
__global__ __launch_bounds__(256) void cvt_tr(const float* __restrict__ in,
                                              unsigned short* __restrict__ out_t,
                                              unsigned short* __restrict__ out_d,
                                              int R, int C) {
  __shared__ unsigned short tile[64][79];
  const int r0 = blockIdx.y * 64, c0 = blockIdx.x * 64;
  const int tr = threadIdx.x >> 4;         // 0..15
  const int tc4 = (threadIdx.x & 15) * 4;  // 0,4,..,60
#pragma unroll
  for (int p = 0; p < 4; ++p) {
    const int r = p * 16 + tr;
    float4 f =
        *reinterpret_cast<const float4*>(in + (size_t)(r0 + r) * C + c0 + tc4);
    unsigned short u0 = bf16_bits(f.x), u1 = bf16_bits(f.y);
    unsigned short u2 = bf16_bits(f.z), u3 = bf16_bits(f.w);
    if (DIRECT) {
      ushort4 u = {u0, u1, u2, u3};
      *reinterpret_cast<ushort4*>(out_d + (size_t)(r0 + r) * C + c0 + tc4) = u;
    }
    tile[r][tc4] = u0;
    tile[r][tc4 + 1] = u1;
    tile[r][tc4 + 2] = u2;
    tile[r][tc4 + 3] = u3;
  }
  __syncthreads();
#pragma unroll
  for (int p = 0; p < 4; ++p) {
    const int c = p * 16 + tr;
    ushort4 u = {tile[tc4][c], tile[tc4 + 1][c], tile[tc4 + 2][c],
                 tile[tc4 + 3][c]};
    *reinterpret_cast<ushort4*>(out_t + (size_t)(c0 + c) * R + r0 + tc4) = u;
  }
}

// ---------------------------------------------------------------------------
// column sums of x (f32 [8192][1024]) in two deterministic passes
// ---------------------------------------------------------------------------
__global__ __launch_bounds__(256) void colsum_part(const float* __restrict__ x,
                                                   float* __restrict__ part) {
  const int b = blockIdx.x;            // 256 blocks x 32 rows
  const int c4 = threadIdx.x * 4;
  float4 acc = {0.f, 0.f, 0.f, 0.f};
  for (int q = 0; q < 32; ++q) {
    float4 f =
        *reinterpret_cast<const float4*>(x + (size_t)(b * 32 + q) * 1024 + c4);
    acc.x += f.x;
    acc.y += f.y;
    acc.z += f.z;
    acc.w += f.w;
  }
  *reinterpret_cast<float4*>(part + (size_t)b * 1024 + c4) = acc;
}

__global__ __launch_bounds__(256) void colsum_final(const float* __restrict__ part,
                                                    float* __restrict__ sv) {
  const int c = blockIdx.x * 256 + threadIdx.x;
  float s = 0.f;
  for (int p = 0; p < 256; ++p) s += part[(size_t)p * 1024 + c];
  sv[c] = s;
}

// u = Wq*s (rows 0..1023 of uw), w = Wk*s (rows 1024..2047); one wave per row
__global__ __launch_bounds__(256) void matvec2(const float* __restrict__ Wq,
                                               const float* __restrict__ Wk,
                                               const float* __restrict__ sv,
                                               float* __restrict__ uw) {
  const int row = blockIdx.x * 4 + (threadIdx.x >> 6);
  const int lane = threadIdx.x & 63;
  const float* W = (row < 1024) ? (Wq + (size_t)row * 1024)
                                : (Wk + (size_t)(row - 1024) * 1024);
  const int c0 = lane * 16;
  float acc = 0.f;
#pragma unroll
  for (int q = 0; q < 4; ++q) {
    float4 wv4 = *reinterpret_cast<const float4*>(W + c0 + q * 4);
    float4 s4 = *reinterpret_cast<const float4*>(sv + c0 + q * 4);
    acc += wv4.x * s4.x + wv4.y * s4.y + wv4.z * s4.z + wv4.w * s4.w;
  }
#pragma unroll
  for (int off = 32; off; off >>= 1) acc += __shfl_xor(acc, off);
  if (lane == 0) uw[row] = acc;
}

// ---------------------------------------------------------------------------
// NT GEMM, 2-phase double-buffered (T3-minimum recipe):
//   prologue STAGE(buf0); per iter: STAGE(buf^1, t+1) -> ds_read+MFMA(buf) ->
//   one __syncthreads() (drains vmcnt(0)+lgkmcnt(0)) -> swap.
//   C[m][n] = scale * sum_k A[m][k]*B[n][k] (+bias); 128x128 tile, BK=64,
//   4 waves, T2 XOR-swizzled LDS via pre-swizzled global source.
// BIAS_MODE: 0 none, 2 bias[col]. OUT_BF16: 1 -> bf16 C. XCD_SWZ: T1 swizzle.
// ---------------------------------------------------------------------------
template <int BIAS_MODE, int OUT_BF16, int XCD_SWZ>
__global__ __launch_bounds__(256, 2) void gemm_nt(
    const bf16* __restrict__ A, const bf16* __restrict__ B,
    const float* __restrict__ bias, void* __restrict__ Cout, int M, int N,
    int K, int kChunk, float scale) {
  __shared__ __align__(128) char lds[65536];  // A: [2][16KB] @0, B: @32768
  const int tid = threadIdx.x;
  const int lane = tid & 63;
  const int wv = tid >> 6;
  const int wm = wv >> 1, wn = wv & 1;

  int mt, nt;
  if (XCD_SWZ) {
    int lin = blockIdx.y * gridDim.x + blockIdx.x;
    int cpx = (gridDim.x * gridDim.y) >> 3;  // nwg % 8 == 0 required
    int swz = (lin & 7) * cpx + (lin >> 3);
    nt = swz % gridDim.x;
    mt = swz / gridDim.x;
  } else {
    nt = blockIdx.x;
    mt = blockIdx.y;
  }
  const int m0 = mt * 128, n0 = nt * 128;
  const int kBegin = blockIdx.z * kChunk;

  const char* srcA[4];
  const char* srcB[4];
  int dstOff[4];
#pragma unroll
  for (int t = 0; t < 4; ++t) {
    int o = wv * 4096 + t * 1024 + lane * 16;  // linear LDS byte offset
    int row = o >> 7;                          // tile row (128B per row)
    int gcb = (o & 127) ^ ((row & 7) << 4);    // inverse-swizzled global col
    srcA[t] = (const char*)A + ((size_t)(m0 + row) * K + kBegin) * 2 + gcb;
    srcB[t] = (const char*)B + ((size_t)(n0 + row) * K + kBegin) * 2 + gcb;
    dstOff[t] = wv * 4096 + t * 1024;
  }

  const int xorv = (lane & 7) << 4;
  const int rowOff = (lane & 15) * 128;
  const int colHi = (lane >> 4) << 4;

  // prologue: stage tile 0 into buf 0
#pragma unroll
  for (int t = 0; t < 4; ++t) gload_lds16(srcA[t], lds + dstOff[t]);
#pragma unroll
  for (int t = 0; t < 4; ++t) gload_lds16(srcB[t], lds + 32768 + dstOff[t]);
#pragma unroll
  for (int t = 0; t < 4; ++t) {
    srcA[t] += 128;
    srcB[t] += 128;
  }
  __syncthreads();

  f32x4 acc[4][4] = {};
  const int nk = kChunk >> 6;
  int cur = 0;
  for (int kt = 0; kt < nk; ++kt) {
    if (kt + 1 < nk) {  // prefetch next tile into the other buffer
      const int nb = (cur ^ 1) * 16384;
#pragma unroll
      for (int t = 0; t < 4; ++t) gload_lds16(srcA[t], lds + nb + dstOff[t]);
#pragma unroll
      for (int t = 0; t < 4; ++t)
        gload_lds16(srcB[t], lds + 32768 + nb + dstOff[t]);
#pragma unroll
      for (int t = 0; t < 4; ++t) {
        srcA[t] += 128;
        srcB[t] += 128;
      }
    }
    const char* baseA = lds + cur * 16384;
    const char* baseB = lds + 32768 + cur * 16384;
#pragma unroll
    for (int h = 0; h < 2; ++h) {
      const int kk64 = h * 64;
      bf16x8 af[4], bfr[4];
#pragma unroll
      for (int f = 0; f < 4; ++f)
        af[f] = *reinterpret_cast<const bf16x8*>(
            baseA + ((wm * 64 + f * 16) * 128) + rowOff + ((kk64 + colHi) ^ xorv));
#pragma unroll
      for (int f = 0; f < 4; ++f)
        bfr[f] = *reinterpret_cast<const bf16x8*>(
            baseB + ((wn * 64 + f * 16) * 128) + rowOff + ((kk64 + colHi) ^ xorv));
      __builtin_amdgcn_s_setprio(1);
#pragma unroll
      for (int m = 0; m < 4; ++m)
#pragma unroll
        for (int n = 0; n < 4; ++n)
          acc[m][n] = __builtin_amdgcn_mfma_f32_16x16x32_bf16(af[m], bfr[n],
                                                              acc[m][n], 0, 0, 0);
      __builtin_amdgcn_s_setprio(0);
    }
    __syncthreads();  // next-tile staging drained; all waves done reading cur
    cur ^= 1;
  }

  // epilogue: C/D layout col=lane&15, row=(lane>>4)*4+r (guide §3, m89)
  char* Cbase = (char*)Cout + (size_t)blockIdx.z * M * N * (OUT_BF16 ? 2 : 4);
#pragma unroll
  for (int m = 0; m < 4; ++m) {
    const int grow = m0 + wm * 64 + m * 16 + ((lane >> 4) << 2);
#pragma unroll
    for (int n = 0; n < 4; ++n) {
      const int gcol = n0 + wn * 64 + n * 16 + (lane & 15);
#pragma unroll
      for (int r = 0; r < 4; ++r) {
        float v = acc[m][n][r] * scale;
        if (BIAS_MODE == 2) v += bias[gcol];
        if (OUT_BF16)
          ((bf16*)Cbase)[(size_t)(grow + r) * N + gcol] = __float2bfloat16(v);
        else
          ((float*)Cbase)[(size_t)(grow + r) * N + gcol] = v;
      }
    }
  }
}

// ---------------------------------------------------------------------------
// sum 4 split-K partials of G = x^T x, emit Gext = [bf16(G) | bf16(residual)]
// ---------------------------------------------------------------------------
__global__ __launch_bounds__(256) void gext_sum(const float* __restrict__ Sp,
                                                unsigned short* __restrict__ Gext) {
  const int k = blockIdx.x;
  const int c4 = threadIdx.x * 4;
  float g[4] = {0.f, 0.f, 0.f, 0.f};
#pragma unroll
  for (int z = 0; z < 4; ++z) {
    float4 f = *reinterpret_cast<const float4*>(Sp + ((size_t)z << 20) +
                                                (size_t)k * 1024 + c4);
    g[0] += f.x;
    g[1] += f.y;
    g[2] += f.z;
    g[3] += f.w;
  }
  ushort4 hi, lo;
  unsigned short* h = &hi.x;
  unsigned short* l = &lo.x;
#pragma unroll
  for (int q = 0; q < 4; ++q) {
    unsigned short b = bf16_bits(g[q]);
    h[q] = b;
    l[q] = bf16_bits(g[q] - b2f(b));
  }
  *reinterpret_cast<ushort4*>(Gext + (size_t)k * 2048 + c4) = hi;
  *reinterpret_cast<ushort4*>(Gext + (size_t)k * 2048 + 1024 + c4) = lo;
}

// ---------------------------------------------------------------------------
// row-softmax of St with rank-1 bias corrections:
// v[i] = norm*(St[j][i] + bk[j]*u[i] + (w[j]+8192*bk[j])*bq[i]); At[j][i] bf16
// ---------------------------------------------------------------------------
__global__ __launch_bounds__(256) void softmax_corr(
    const float* __restrict__ St, const float* __restrict__ uw,
    const float* __restrict__ bq, const float* __restrict__ bk,
    bf16* __restrict__ At) {
  const int j = blockIdx.x;
  const int tid = threadIdx.x;
  const int lane = tid & 63, wv = tid >> 6;
  const float a1 = bk[j];
  const float a2 = uw[1024 + j] + 8192.0f * a1;
  const float norm = 0.03125f;  // 1/sqrt(1024)
  float v[4];
#pragma unroll
  for (int t = 0; t < 4; ++t) {
    const int i = tid + 256 * t;
    v[t] = norm * (St[(size_t)j * 1024 + i] + a1 * uw[i] + a2 * bq[i]);
  }
  float m = fmaxf(fmaxf(v[0], v[1]), fmaxf(v[2], v[3]));
#pragma unroll
  for (int off = 32; off; off >>= 1) m = fmaxf(m, __shfl_xor(m, off));
  __shared__ float red[8];
  if (lane == 0) red[wv] = m;
  __syncthreads();
  m = fmaxf(fmaxf(red[0], red[1]), fmaxf(red[2], red[3]));
  float p[4], s = 0.f;
#pragma unroll
  for (int t = 0; t < 4; ++t) {
    p[t] = __expf(v[t] - m);
    s += p[t];
  }
#pragma unroll
  for (int off = 32; off; off >>= 1) s += __shfl_xor(s, off);
  if (lane == 0) red[4 + wv] = s;
  __syncthreads();
  const float inv = 1.f / (red[4] + red[5] + red[6] + red[7]);
#pragma unroll
  for (int t = 0; t < 4; ++t)
    At[(size_t)j * 1024 + tid + 256 * t] = __float2bfloat16(p[t] * inv);
}

// r[j] = sum_m At[j][m] * bv[m]; one wave per row
__global__ __launch_bounds__(256) void matvec_r(const bf16* __restrict__ At,
                                                const float* __restrict__ bv,
                                                float* __restrict__ r) {
  const int row = blockIdx.x * 4 + (threadIdx.x >> 6);
  const int lane = threadIdx.x & 63;
  const unsigned short* a =
      (const unsigned short*)At + (size_t)row * 1024 + lane * 16;
  bf16x8 a0 = *reinterpret_cast<const bf16x8*>(a);
  bf16x8 a1 = *reinterpret_cast<const bf16x8*>(a + 8);
  float acc = 0.f;
#pragma unroll
  for (int q = 0; q < 8; ++q) acc += b2f((unsigned short)a0[q]) * bv[lane * 16 + q];
#pragma unroll
  for (int q = 0; q < 8; ++q)
    acc += b2f((unsigned short)a1[q]) * bv[lane * 16 + 8 + q];
#pragma unroll
  for (int off = 32; off; off >>= 1) acc += __shfl_xor(acc, off);
  if (lane == 0) r[row] = acc;
}

// ---------------------------------------------------------------------------
extern "C" void kernel_launch(void* const* d_in, const int* in_sizes, int n_in,
                              void* d_out, int out_size, void* d_ws,
                              size_t ws_size, hipStream_t stream) {
  const float* x = (const float*)d_in[0];
  const float* Wq = (const float*)d_in[1];
  const float* bq = (const float*)d_in[2];
  const float* Wk = (const float*)d_in[3];
  const float* bk = (const float*)d_in[4];
  const float* Wv = (const float*)d_in[5];
  const float* bv = (const float*)d_in[6];
  (void)in_sizes;
  (void)n_in;
  (void)out_size;
  (void)ws_size;

  char* ws = (char*)d_ws;
  const size_t MB = 1ull << 20;
  bf16* xb = (bf16*)(ws);                        // [8192][1024], 16MB, live to end
  bf16* xt = (bf16*)(ws + 16 * MB);              // [1024][8192], 16MB
  float* SpG = (float*)(ws + 32 * MB);           // [4][1024][1024] f32, 16MB
  bf16* Wkext = (bf16*)(ws + 48 * MB);           // [1024][2048], 4MB
  bf16* Wqb = (bf16*)(ws + 52 * MB);             // [1024][1024], 2MB
  bf16* Wvtb = (bf16*)(ws + 54 * MB);            // [1024][1024] (Wv^T), 2MB
  bf16* Gext = (bf16*)(ws + 56 * MB);            // [1024][2048], 4MB
  bf16* T1b = (bf16*)(ws + 60 * MB);             // [1024][1024], 2MB
  float* Stc = (float*)(ws + 62 * MB);           // [1024][1024] f32, 4MB
  bf16* At = (bf16*)(ws + 66 * MB);              // [1024][1024], 2MB
  bf16* Ftb = (bf16*)(ws + 68 * MB);             // [1024][1024], 2MB
  float* sv = (float*)(ws + 70 * MB);            // [1024]
  float* uw = (float*)(ws + 70 * MB + 4096);     // [2048]
  float* rv = (float*)(ws + 70 * MB + 12288);    // [1024]
  float* part = (float*)(ws + 70 * MB + 16384);  // [256][1024] f32, 1MB

  // x -> xb (bf16) + xt (bf16 transpose)
  cvt_tr<1><<<dim3(16, 128), 256, 0, stream>>>(x, (unsigned short*)xt,
                                               (unsigned short*)xb, 8192, 1024);
  // weights
  cvt_dup<<<1024, 256, 0, stream>>>(Wk, (unsigned short*)Wkext);
  cvt_f32_bf16<<<1024, 256, 0, stream>>>(Wq, (unsigned short*)Wqb, 262144);
  cvt_tr<0><<<dim3(16, 16), 256, 0, stream>>>(Wv, (unsigned short*)Wvtb, nullptr,
                                              1024, 1024);
  // s = colsum(x); u = Wq s, w = Wk s
  colsum_part<<<256, 256, 0, stream>>>(x, part);
  colsum_final<<<4, 256, 0, stream>>>(part, sv);
  matvec2<<<512, 256, 0, stream>>>(Wq, Wk, sv, uw);

  // G = x^T x : NT(xt, xt), K=8192, split-K=4 -> f32 partials
  gemm_nt<0, 0, 1><<<dim3(8, 8, 4), 256, 0, stream>>>(xt, xt, nullptr, SpG, 1024,
                                                      1024, 8192, 2048, 1.0f);
  // Gext = [bf16(G) | residual]
  gext_sum<<<1024, 256, 0, stream>>>(SpG, (unsigned short*)Gext);
  // T1 = Wk * G  (uses G symmetric): NT(Wkext, Gext), K=2048 -> bf16
  gemm_nt<0, 1, 1><<<dim3(8, 8), 256, 0, stream>>>(Wkext, Gext, nullptr, T1b,
                                                   1024, 1024, 2048, 2048, 1.0f);
  // St core = T1 * Wq^T : NT(T1b, Wqb) -> f32
  gemm_nt<0, 0, 1><<<dim3(8, 8), 256, 0, stream>>>(T1b, Wqb, nullptr, Stc, 1024,
                                                   1024, 1024, 1024, 1.0f);
  // atten^T with rank-1 corrections
  softmax_corr<<<1024, 256, 0, stream>>>(Stc, uw, bq, bk, At);
  // r[j] = bv . atten[:,j]
  matvec_r<<<256, 256, 0, stream>>>(At, bv, rv);
  // F^T = NT(At, Wvt) -> bf16   (F = Wv^T atten)
  gemm_nt<0, 1, 1><<<dim3(8, 8), 256, 0, stream>>>(At, Wvtb, nullptr, Ftb, 1024,
                                                   1024, 1024, 1024, 1.0f);
  // out = x * F + 1*r^T : NT(xb, Ftb) + bias[col] -> f32 d_out
  gemm_nt<2, 0, 1><<<dim3(8, 64), 256, 0, stream>>>(xb, Ftb, rv, d_out, 8192,
                                                    1024, 1024, 1024, 1.0f);
}

// Round 4
// 133.524 us; speedup vs baseline: 1.1073x; 1.1073x over previous
//
#include <hip/hip_runtime.h>
#include <hip/hip_bf16.h>
#include <stdint.h>

using bf16 = __hip_bfloat16;
typedef __attribute__((ext_vector_type(8))) short bf16x8;
typedef __attribute__((ext_vector_type(4))) float f32x4;

// ---------------------------------------------------------------------------
// helpers
// ---------------------------------------------------------------------------
__device__ __forceinline__ void gload_lds16(const void* g, void* l) {
  __builtin_amdgcn_global_load_lds(
      (__attribute__((address_space(1))) void*)(g),
      (__attribute__((address_space(3))) void*)(l), 16, 0, 0);
}

__device__ __forceinline__ unsigned short bf16_bits(float f) {
  bf16 b = __float2bfloat16(f);
  return *reinterpret_cast<unsigned short*>(&b);
}

__device__ __forceinline__ float b2f(unsigned short u) {
  union { unsigned int i; float f; } x;
  x.i = ((unsigned int)u) << 16;
  return x.f;
}

// ---------------------------------------------------------------------------
// pre_x: one pass over x producing xb (bf16), xt (bf16 transpose), and
// 64-row column partial sums (part[128][1024]). 64x64 tiles, grid (16,128).
// ---------------------------------------------------------------------------
__global__ __launch_bounds__(256) void pre_x(const float* __restrict__ x,
                                             unsigned short* __restrict__ xb,
                                             unsigned short* __restrict__ xt,
                                             float* __restrict__ part) {
  __shared__ unsigned short tile[64][79];
  __shared__ float cw[4][64];
  const int r0 = blockIdx.y * 64, c0 = blockIdx.x * 64;
  const int tr = threadIdx.x >> 4;         // 0..15
  const int tc4 = (threadIdx.x & 15) * 4;  // 0,4,..,60
  float ca0 = 0.f, ca1 = 0.f, ca2 = 0.f, ca3 = 0.f;
#pragma unroll
  for (int p = 0; p < 4; ++p) {
    const int r = p * 16 + tr;
    float4 f =
        *reinterpret_cast<const float4*>(x + (size_t)(r0 + r) * 1024 + c0 + tc4);
    unsigned short u0 = bf16_bits(f.x), u1 = bf16_bits(f.y);
    unsigned short u2 = bf16_bits(f.z), u3 = bf16_bits(f.w);
    ushort4 u = {u0, u1, u2, u3};
    *reinterpret_cast<ushort4*>(xb + (size_t)(r0 + r) * 1024 + c0 + tc4) = u;
    tile[r][tc4] = u0;
    tile[r][tc4 + 1] = u1;
    tile[r][tc4 + 2] = u2;
    tile[r][tc4 + 3] = u3;
    ca0 += f.x;
    ca1 += f.y;
    ca2 += f.z;
    ca3 += f.w;
  }
  // reduce col partials over tr within wave (lanes b, b^16, b^32 span 4 tr's)
  ca0 += __shfl_xor(ca0, 16); ca0 += __shfl_xor(ca0, 32);
  ca1 += __shfl_xor(ca1, 16); ca1 += __shfl_xor(ca1, 32);
  ca2 += __shfl_xor(ca2, 16); ca2 += __shfl_xor(ca2, 32);
  ca3 += __shfl_xor(ca3, 16); ca3 += __shfl_xor(ca3, 32);
  const int lane = threadIdx.x & 63, wv = threadIdx.x >> 6;
  if (lane < 16) {
    cw[wv][lane * 4] = ca0;
    cw[wv][lane * 4 + 1] = ca1;
    cw[wv][lane * 4 + 2] = ca2;
    cw[wv][lane * 4 + 3] = ca3;
  }
  __syncthreads();
  if (threadIdx.x < 64) {
    float s = cw[0][threadIdx.x] + cw[1][threadIdx.x] + cw[2][threadIdx.x] +
              cw[3][threadIdx.x];
    part[(size_t)blockIdx.y * 1024 + c0 + threadIdx.x] = s;
  }
#pragma unroll
  for (int p = 0; p < 4; ++p) {
    const int c = p * 16 + tr;
    ushort4 u = {tile[tc4][c], tile[tc4 + 1][c], tile[tc4 + 2][c],
                 tile[tc4 + 3][c]};
    *reinterpret_cast<ushort4*>(xt + (size_t)(c0 + c) * 8192 + r0 + tc4) = u;
  }
}

// ---------------------------------------------------------------------------
// wprep: z=0 Wq->Wqb (bf16), z=1 Wk->Wkext ([W|W] dup), z=2 Wv->Wvtb (transp)
// grid (16,16,3)
// ---------------------------------------------------------------------------
__global__ __launch_bounds__(256) void wprep(
    const float* __restrict__ Wq, const float* __restrict__ Wk,
    const float* __restrict__ Wv, unsigned short* __restrict__ Wqb,
    unsigned short* __restrict__ Wkext, unsigned short* __restrict__ Wvtb) {
  __shared__ unsigned short tile[64][79];
  const int r0 = blockIdx.y * 64, c0 = blockIdx.x * 64;
  const int tr = threadIdx.x >> 4;
  const int tc4 = (threadIdx.x & 15) * 4;
  if (blockIdx.z < 2) {
    const float* W = (blockIdx.z == 0) ? Wq : Wk;
#pragma unroll
    for (int p = 0; p < 4; ++p) {
      const int r = r0 + p * 16 + tr;
      float4 f = *reinterpret_cast<const float4*>(W + (size_t)r * 1024 + c0 + tc4);
      ushort4 u = {bf16_bits(f.x), bf16_bits(f.y), bf16_bits(f.z), bf16_bits(f.w)};
      if (blockIdx.z == 0) {
        *reinterpret_cast<ushort4*>(Wqb + (size_t)r * 1024 + c0 + tc4) = u;
      } else {
        *reinterpret_cast<ushort4*>(Wkext + (size_t)r * 2048 + c0 + tc4) = u;
        *reinterpret_cast<ushort4*>(Wkext + (size_t)r * 2048 + 1024 + c0 + tc4) = u;
      }
    }
  } else {
#pragma unroll
    for (int p = 0; p < 4; ++p) {
      const int r = p * 16 + tr;
      float4 f =
          *reinterpret_cast<const float4*>(Wv + (size_t)(r0 + r) * 1024 + c0 + tc4);
      tile[r][tc4] = bf16_bits(f.x);
      tile[r][tc4 + 1] = bf16_bits(f.y);
      tile[r][tc4 + 2] = bf16_bits(f.z);
      tile[r][tc4 + 3] = bf16_bits(f.w);
    }
    __syncthreads();
#pragma unroll
    for (int p = 0; p < 4; ++p) {
      const int c = p * 16 + tr;
      ushort4 u = {tile[tc4][c], tile[tc4 + 1][c], tile[tc4 + 2][c],
                   tile[tc4 + 3][c]};
      *reinterpret_cast<ushort4*>(Wvtb + (size_t)(c0 + c) * 1024 + r0 + tc4) = u;
    }
  }
}

// sv[c] = sum over 128 row-stripes of part
__global__ __launch_bounds__(256) void colsum_final(const float* __restrict__ part,
                                                    float* __restrict__ sv) {
  const int c = blockIdx.x * 256 + threadIdx.x;
  float s = 0.f;
  for (int p = 0; p < 128; ++p) s += part[(size_t)p * 1024 + c];
  sv[c] = s;
}

// u = Wq*s (rows 0..1023 of uw), w = Wk*s (rows 1024..2047); one wave per row
__global__ __launch_bounds__(256) void matvec2(const float* __restrict__ Wq,
                                               const float* __restrict__ Wk,
                                               const float* __restrict__ sv,
                                               float* __restrict__ uw) {
  const int row = blockIdx.x * 4 + (threadIdx.x >> 6);
  const int lane = threadIdx.x & 63;
  const float* W = (row < 1024) ? (Wq + (size_t)row * 1024)
                                : (Wk + (size_t)(row - 1024) * 1024);
  const int c0 = lane * 16;
  float acc = 0.f;
#pragma unroll
  for (int q = 0; q < 4; ++q) {
    float4 wv4 = *reinterpret_cast<const float4*>(W + c0 + q * 4);
    float4 s4 = *reinterpret_cast<const float4*>(sv + c0 + q * 4);
    acc += wv4.x * s4.x + wv4.y * s4.y + wv4.z * s4.z + wv4.w * s4.w;
  }
#pragma unroll
  for (int off = 32; off; off >>= 1) acc += __shfl_xor(acc, off);
  if (lane == 0) uw[row] = acc;
}

// ---------------------------------------------------------------------------
// NT GEMM, 2-phase double-buffered; 128x128 tile, BK=64, 4 waves,
// T2 XOR-swizzled LDS via pre-swizzled global source, T1 XCD swizzle.
// BIAS_MODE: 0 none, 2 bias[col]. OUT_BF16: 1 -> bf16 C.
// ---------------------------------------------------------------------------
template <int BIAS_MODE, int OUT_BF16, int XCD_SWZ>
__global__ __launch_bounds__(256, 2) void gemm_nt(
    const bf16* __restrict__ A, const bf16* __restrict__ B,
    const float* __restrict__ bias, void* __restrict__ Cout, int M, int N,
    int K, int kChunk, float scale) {
  __shared__ __align__(128) char lds[65536];  // A: [2][16KB] @0, B: @32768
  const int tid = threadIdx.x;
  const int lane = tid & 63;
  const int wv = tid >> 6;
  const int wm = wv >> 1, wn = wv & 1;

  int mt, nt;
  if (XCD_SWZ) {
    int lin = blockIdx.y * gridDim.x + blockIdx.x;
    int cpx = (gridDim.x * gridDim.y) >> 3;  // nwg % 8 == 0 required
    int swz = (lin & 7) * cpx + (lin >> 3);
    nt = swz % gridDim.x;
    mt = swz / gridDim.x;
  } else {
    nt = blockIdx.x;
    mt = blockIdx.y;
  }
  const int m0 = mt * 128, n0 = nt * 128;
  const int kBegin = blockIdx.z * kChunk;

  const char* srcA[4];
  const char* srcB[4];
  int dstOff[4];
#pragma unroll
  for (int t = 0; t < 4; ++t) {
    int o = wv * 4096 + t * 1024 + lane * 16;  // linear LDS byte offset
    int row = o >> 7;                          // tile row (128B per row)
    int gcb = (o & 127) ^ ((row & 7) << 4);    // inverse-swizzled global col
    srcA[t] = (const char*)A + ((size_t)(m0 + row) * K + kBegin) * 2 + gcb;
    srcB[t] = (const char*)B + ((size_t)(n0 + row) * K + kBegin) * 2 + gcb;
    dstOff[t] = wv * 4096 + t * 1024;
  }

  const int xorv = (lane & 7) << 4;
  const int rowOff = (lane & 15) * 128;
  const int colHi = (lane >> 4) << 4;

  // prologue: stage tile 0 into buf 0
#pragma unroll
  for (int t = 0; t < 4; ++t) gload_lds16(srcA[t], lds + dstOff[t]);
#pragma unroll
  for (int t = 0; t < 4; ++t) gload_lds16(srcB[t], lds + 32768 + dstOff[t]);
#pragma unroll
  for (int t = 0; t < 4; ++t) {
    srcA[t] += 128;
    srcB[t] += 128;
  }
  __syncthreads();

  f32x4 acc[4][4] = {};
  const int nk = kChunk >> 6;
  int cur = 0;
  for (int kt = 0; kt < nk; ++kt) {
    if (kt + 1 < nk) {  // prefetch next tile into the other buffer
      const int nb = (cur ^ 1) * 16384;
#pragma unroll
      for (int t = 0; t < 4; ++t) gload_lds16(srcA[t], lds + nb + dstOff[t]);
#pragma unroll
      for (int t = 0; t < 4; ++t)
        gload_lds16(srcB[t], lds + 32768 + nb + dstOff[t]);
#pragma unroll
      for (int t = 0; t < 4; ++t) {
        srcA[t] += 128;
        srcB[t] += 128;
      }
    }
    const char* baseA = lds + cur * 16384;
    const char* baseB = lds + 32768 + cur * 16384;
#pragma unroll
    for (int h = 0; h < 2; ++h) {
      const int kk64 = h * 64;
      bf16x8 af[4], bfr[4];
#pragma unroll
      for (int f = 0; f < 4; ++f)
        af[f] = *reinterpret_cast<const bf16x8*>(
            baseA + ((wm * 64 + f * 16) * 128) + rowOff + ((kk64 + colHi) ^ xorv));
#pragma unroll
      for (int f = 0; f < 4; ++f)
        bfr[f] = *reinterpret_cast<const bf16x8*>(
            baseB + ((wn * 64 + f * 16) * 128) + rowOff + ((kk64 + colHi) ^ xorv));
      __builtin_amdgcn_s_setprio(1);
#pragma unroll
      for (int m = 0; m < 4; ++m)
#pragma unroll
        for (int n = 0; n < 4; ++n)
          acc[m][n] = __builtin_amdgcn_mfma_f32_16x16x32_bf16(af[m], bfr[n],
                                                              acc[m][n], 0, 0, 0);
      __builtin_amdgcn_s_setprio(0);
    }
    __syncthreads();  // staged loads drained; all waves done reading cur
    cur ^= 1;
  }

  // epilogue: C/D layout col=lane&15, row=(lane>>4)*4+r (guide §3, m89)
  char* Cbase = (char*)Cout + (size_t)blockIdx.z * M * N * (OUT_BF16 ? 2 : 4);
#pragma unroll
  for (int m = 0; m < 4; ++m) {
    const int grow = m0 + wm * 64 + m * 16 + ((lane >> 4) << 2);
#pragma unroll
    for (int n = 0; n < 4; ++n) {
      const int gcol = n0 + wn * 64 + n * 16 + (lane & 15);
#pragma unroll
      for (int r = 0; r < 4; ++r) {
        float v = acc[m][n][r] * scale;
        if (BIAS_MODE == 2) v += bias[gcol];
        if (OUT_BF16)
          ((bf16*)Cbase)[(size_t)(grow + r) * N + gcol] = __float2bfloat16(v);
        else
          ((float*)Cbase)[(size_t)(grow + r) * N + gcol] = v;
      }
    }
  }
}

// ---------------------------------------------------------------------------
// sum 8 split-K partials of G = x^T x, emit Gext = [bf16(G) | bf16(residual)]
// ---------------------------------------------------------------------------
__global__ __launch_bounds__(256) void gext_sum(const float* __restrict__ Sp,
                                                unsigned short* __restrict__ Gext) {
  const int k = blockIdx.x;
  const int c4 = threadIdx.x * 4;
  float g[4] = {0.f, 0.f, 0.f, 0.f};
#pragma unroll
  for (int z = 0; z < 8; ++z) {
    float4 f = *reinterpret_cast<const float4*>(Sp + ((size_t)z << 20) +
                                                (size_t)k * 1024 + c4);
    g[0] += f.x;
    g[1] += f.y;
    g[2] += f.z;
    g[3] += f.w;
  }
  ushort4 hi, lo;
  unsigned short* h = &hi.x;
  unsigned short* l = &lo.x;
#pragma unroll
  for (int q = 0; q < 4; ++q) {
    unsigned short b = bf16_bits(g[q]);
    h[q] = b;
    l[q] = bf16_bits(g[q] - b2f(b));
  }
  *reinterpret_cast<ushort4*>(Gext + (size_t)k * 2048 + c4) = hi;
  *reinterpret_cast<ushort4*>(Gext + (size_t)k * 2048 + 1024 + c4) = lo;
}

// ---------------------------------------------------------------------------
// row-softmax of St with rank-1 bias corrections + fused r[j] = atten[:,j].bv
// v[i] = norm*(St[j][i] + bk[j]*u[i] + (w[j]+8192*bk[j])*bq[i])
// ---------------------------------------------------------------------------
__global__ __launch_bounds__(256) void softmax_corr_r(
    const float* __restrict__ St, const float* __restrict__ uw,
    const float* __restrict__ bq, const float* __restrict__ bk,
    const float* __restrict__ bv, bf16* __restrict__ At,
    float* __restrict__ rv) {
  const int j = blockIdx.x;
  const int tid = threadIdx.x;
  const int lane = tid & 63, wv = tid >> 6;
  const float a1 = bk[j];
  const float a2 = uw[1024 + j] + 8192.0f * a1;
  const float norm = 0.03125f;  // 1/sqrt(1024)
  float v[4];
#pragma unroll
  for (int t = 0; t < 4; ++t) {
    const int i = tid + 256 * t;
    v[t] = norm * (St[(size_t)j * 1024 + i] + a1 * uw[i] + a2 * bq[i]);
  }
  float m = fmaxf(fmaxf(v[0], v[1]), fmaxf(v[2], v[3]));
#pragma unroll
  for (int off = 32; off; off >>= 1) m = fmaxf(m, __shfl_xor(m, off));
  __shared__ float red[12];
  if (lane == 0) red[wv] = m;
  __syncthreads();
  m = fmaxf(fmaxf(red[0], red[1]), fmaxf(red[2], red[3]));
  float p[4], s = 0.f, pr = 0.f;
#pragma unroll
  for (int t = 0; t < 4; ++t) {
    p[t] = __expf(v[t] - m);
    s += p[t];
    pr += p[t] * bv[tid + 256 * t];
  }
#pragma unroll
  for (int off = 32; off; off >>= 1) {
    s += __shfl_xor(s, off);
    pr += __shfl_xor(pr, off);
  }
  if (lane == 0) {
    red[4 + wv] = s;
    red[8 + wv] = pr;
  }
  __syncthreads();
  const float inv = 1.f / (red[4] + red[5] + red[6] + red[7]);
#pragma unroll
  for (int t = 0; t < 4; ++t)
    At[(size_t)j * 1024 + tid + 256 * t] = __float2bfloat16(p[t] * inv);
  if (tid == 0) rv[j] = (red[8] + red[9] + red[10] + red[11]) * inv;
}

// ---------------------------------------------------------------------------
extern "C" void kernel_launch(void* const* d_in, const int* in_sizes, int n_in,
                              void* d_out, int out_size, void* d_ws,
                              size_t ws_size, hipStream_t stream) {
  const float* x = (const float*)d_in[0];
  const float* Wq = (const float*)d_in[1];
  const float* bq = (const float*)d_in[2];
  const float* Wk = (const float*)d_in[3];
  const float* bk = (const float*)d_in[4];
  const float* Wv = (const float*)d_in[5];
  const float* bv = (const float*)d_in[6];
  (void)in_sizes;
  (void)n_in;
  (void)out_size;
  (void)ws_size;

  char* ws = (char*)d_ws;
  const size_t MB = 1ull << 20;
  bf16* xb = (bf16*)(ws);               // [8192][1024], 16MB
  bf16* xt = (bf16*)(ws + 16 * MB);     // [1024][8192], 16MB
  float* SpG = (float*)(ws + 32 * MB);  // [8][1024][1024] f32, 32MB
  bf16* Wkext = (bf16*)(ws + 64 * MB);  // [1024][2048], 4MB
  bf16* Wqb = (bf16*)(ws + 68 * MB);    // [1024][1024], 2MB
  bf16* Wvtb = (bf16*)(ws + 70 * MB);   // [1024][1024] (Wv^T), 2MB
  bf16* Gext = (bf16*)(ws + 72 * MB);   // [1024][2048], 4MB
  bf16* T1b = (bf16*)(ws + 76 * MB);    // [1024][1024], 2MB
  float* Stc = (float*)(ws + 78 * MB);  // [1024][1024] f32, 4MB
  bf16* At = (bf16*)(ws + 82 * MB);     // [1024][1024], 2MB
  bf16* Ftb = (bf16*)(ws + 84 * MB);    // [1024][1024], 2MB
  float* sv = (float*)(ws + 86 * MB);           // [1024]
  float* uw = (float*)(ws + 86 * MB + 4096);    // [2048]
  float* rv = (float*)(ws + 86 * MB + 16384);   // [1024]
  float* part = (float*)(ws + 87 * MB);         // [128][1024] f32, 512KB

  // 1. x -> xb, xt, column partials (single pass over x)
  pre_x<<<dim3(16, 128), 256, 0, stream>>>(x, (unsigned short*)xb,
                                           (unsigned short*)xt, part);
  // 2. weights: Wq->Wqb, Wk->Wkext(dup), Wv->Wvtb(transpose)
  wprep<<<dim3(16, 16, 3), 256, 0, stream>>>(Wq, Wk, Wv, (unsigned short*)Wqb,
                                             (unsigned short*)Wkext,
                                             (unsigned short*)Wvtb);
  // 3. sv = colsum(x)
  colsum_final<<<4, 256, 0, stream>>>(part, sv);
  // 4. u = Wq s, w = Wk s
  matvec2<<<512, 256, 0, stream>>>(Wq, Wk, sv, uw);
  // 5. G = x^T x : NT(xt, xt), K=8192, split-K=8 -> f32 partials
  gemm_nt<0, 0, 1><<<dim3(8, 8, 8), 256, 0, stream>>>(xt, xt, nullptr, SpG, 1024,
                                                      1024, 8192, 1024, 1.0f);
  // 6. Gext = [bf16(G) | residual]
  gext_sum<<<1024, 256, 0, stream>>>(SpG, (unsigned short*)Gext);
  // 7. T1 = Wk * G : NT(Wkext, Gext), K=2048 -> bf16
  gemm_nt<0, 1, 1><<<dim3(8, 8), 256, 0, stream>>>(Wkext, Gext, nullptr, T1b,
                                                   1024, 1024, 2048, 2048, 1.0f);
  // 8. St core = T1 * Wq^T : NT(T1b, Wqb) -> f32
  gemm_nt<0, 0, 1><<<dim3(8, 8), 256, 0, stream>>>(T1b, Wqb, nullptr, Stc, 1024,
                                                   1024, 1024, 1024, 1.0f);
  // 9. atten^T with rank-1 corrections + r[j] = bv . atten[:,j]
  softmax_corr_r<<<1024, 256, 0, stream>>>(Stc, uw, bq, bk, bv, At, rv);
  // 10. F^T = NT(At, Wvt) -> bf16   (F = Wv^T atten)
  gemm_nt<0, 1, 1><<<dim3(8, 8), 256, 0, stream>>>(At, Wvtb, nullptr, Ftb, 1024,
                                                   1024, 1024, 1024, 1.0f);
  // 11. out = x * F + 1*r^T : NT(xb, Ftb) + bias[col] -> f32 d_out
  gemm_nt<2, 0, 1><<<dim3(8, 64), 256, 0, stream>>>(xb, Ftb, rv, d_out, 8192,
                                                    1024, 1024, 1024, 1.0f);
}